// Round 3
// baseline (370.424 us; speedup 1.0000x reference)
//
#include <hip/hip_runtime.h>
#include <cstdint>

#define IW 1536
#define IH 1536
#define NPIX (IW*IH)
#define NBLK 576
#define TOPK 100
#define NSHARD 64
#define TCAP 1024
#define ACAP 128
#define BF_INF16 0x7F7Fu  // bf16 max-finite stand-in for +inf (avoids inf-inf=NaN in comparator)

typedef unsigned u32; typedef unsigned long long u64; typedef unsigned short u16;

// ---- workspace layout (u32 offsets) ----
#define P1 0                 // partials MSD: [block][512]  = 294912 u32
#define P2 294912            // partials LSD: same
#define OMSD 589824          // D0 D1 Shi0 Shi1
#define OTHR 589828          // thr0 thr1
#define OCNTA 589830         // 2
#define OCNTT 589832         // 128
#define OLISTA 589960        // 2*128 u64 (byte off 2359840, 8-aligned)
#define OLISTT 590472        // 2*64*1024 u32

__device__ __forceinline__ u32 enc16(u32 b){ b &= 0xFFFFu; return (b & 0x8000u) ? ((~b)&0xFFFFu) : (b|0x8000u); }
__device__ __forceinline__ u32 dec16(u32 e){ return (e & 0x8000u) ? (e^0x8000u) : ((~e)&0xFFFFu); }
__device__ __forceinline__ float up16(u32 b){ return __uint_as_float((b&0xFFFFu)<<16); }
__device__ __forceinline__ u16 f2bf(float f){ u32 u=__float_as_uint(f); return (u16)((u + 0x7FFFu + ((u>>16)&1u))>>16); }

// peak test on bf16 bit codes (enc16 is order-isomorphic to value)
__device__ __forceinline__ void peak_enc(const u32* __restrict__ hm, int x, int y,
                                         u32& e0, u32& e1, bool& p0, bool& p1){
  u32 v = hm[y*IW+x];
  e0 = enc16(v); e1 = enc16(v>>16);
  u32 m0=0, m1=0;
  int ylo = y?y-1:0, yhi = (y<IH-1)?y+1:y;
  int xlo = x?x-1:0, xhi = (x<IW-1)?x+1:x;
  for(int yy=ylo; yy<=yhi; ++yy)
    for(int xx=xlo; xx<=xhi; ++xx){
      if(yy==y && xx==x) continue;
      u32 n = hm[yy*IW+xx];
      u32 a = enc16(n), b = enc16(n>>16);
      m0 = a>m0?a:m0; m1 = b>m1?b:m1;
    }
  p0 = (e0 >= m0); p1 = (e1 >= m1);
}

__global__ void zero_kernel(u32* __restrict__ ws){
  int i = threadIdx.x;               // zero cntA(2) + cntT(128)
  if(i < 130) ws[OCNTA + i] = 0u;
}

// MSD histogram (enc>>8), per-block LDS, non-atomic partial flush
__global__ __launch_bounds__(1024) void hist_msd_kernel(const u32* __restrict__ hm, u32* __restrict__ ws){
  __shared__ u32 lh[512];
  int tid = threadIdx.x, bx = blockIdx.x;
  if(tid < 512) lh[tid] = 0u;
  __syncthreads();
  for(int k=0;k<4;++k){
    int p = bx*4096 + k*1024 + tid;
    int y = p / IW, x = p - y*IW;
    u32 e0,e1; bool p0,p1;
    peak_enc(hm,x,y,e0,e1,p0,p1);
    if(p0) atomicAdd(&lh[e0>>8], 1u);
    if(p1) atomicAdd(&lh[256 + (e1>>8)], 1u);
  }
  __syncthreads();
  if(tid < 512) ws[P1 + bx*512 + tid] = lh[tid];
}

// reduce MSD partials, pick digit D (and count strictly above, Shi) per channel
__global__ __launch_bounds__(512) void sel_msd_kernel(u32* __restrict__ ws){
  __shared__ u32 hh[512];
  int t = threadIdx.x;
  u32 s = 0;
  for(int b=0;b<NBLK;++b) s += ws[P1 + b*512 + t];
  hh[t] = s;
  __syncthreads();
  if(t < 2){
    const u32* h = hh + t*256;
    u32 above = 0; int D = 0;
    for(int b=255;b>=1;--b){
      if(above + h[b] >= (u32)TOPK){ D = b; goto done; }
      above += h[b];
    }
    D = 0;
done:
    ((int*)ws)[OMSD + t] = D;
    ((int*)ws)[OMSD + 2 + t] = (int)above;
  }
}

// LSD histogram within MSD class D
__global__ __launch_bounds__(1024) void hist_lsd_kernel(const u32* __restrict__ hm, u32* __restrict__ ws){
  __shared__ u32 lh[512];
  int tid = threadIdx.x, bx = blockIdx.x;
  int D0 = ((const int*)ws)[OMSD], D1 = ((const int*)ws)[OMSD+1];
  if(tid < 512) lh[tid] = 0u;
  __syncthreads();
  for(int k=0;k<4;++k){
    int p = bx*4096 + k*1024 + tid;
    int y = p / IW, x = p - y*IW;
    u32 e0,e1; bool p0,p1;
    peak_enc(hm,x,y,e0,e1,p0,p1);
    if(p0 && (int)(e0>>8)==D0) atomicAdd(&lh[e0&255], 1u);
    if(p1 && (int)(e1>>8)==D1) atomicAdd(&lh[256 + (e1&255)], 1u);
  }
  __syncthreads();
  if(tid < 512) ws[P2 + bx*512 + tid] = lh[tid];
}

__global__ __launch_bounds__(512) void sel_lsd_kernel(u32* __restrict__ ws){
  __shared__ u32 hh[512];
  int t = threadIdx.x;
  u32 s = 0;
  for(int b=0;b<NBLK;++b) s += ws[P2 + b*512 + t];
  hh[t] = s;
  __syncthreads();
  if(t < 2){
    const u32* h = hh + t*256;
    int D = ((const int*)ws)[OMSD + t];
    int Shi = ((const int*)ws)[OMSD + 2 + t];
    int need2 = TOPK - Shi;            // >=1 by construction
    u32 above = 0; int L = 0;
    for(int b=255;b>=1;--b){
      if((int)(above + h[b]) >= need2){ L = b; goto done; }
      above += h[b];
    }
    L = 0;
done:
    ((int*)ws)[OTHR + t] = (D<<8) | L;
  }
}

// collect strictly-above into listA, exact-tie indices into sharded listT
__global__ __launch_bounds__(1024) void collect_kernel(const u32* __restrict__ hm, u32* __restrict__ ws){
  int tid = threadIdx.x, bx = blockIdx.x;
  u32 thr0 = (u32)((const int*)ws)[OTHR], thr1 = (u32)((const int*)ws)[OTHR+1];
  u64* listA = (u64*)(ws + OLISTA);
  for(int k=0;k<4;++k){
    int p = bx*4096 + k*1024 + tid;
    int y = p / IW, x = p - y*IW;
    u32 e0,e1; bool p0,p1;
    peak_enc(hm,x,y,e0,e1,p0,p1);
    int sh = y & (NSHARD-1);
    if(p0){
      if(e0 > thr0){
        u32 pos = atomicAdd(&ws[OCNTA], 1u);
        if(pos < ACAP) listA[pos] = ((u64)e0<<32) | (u32)(~(u32)p);
      } else if(e0 == thr0){
        u32 pos = atomicAdd(&ws[OCNTT + sh], 1u);
        if(pos < TCAP) ws[OLISTT + sh*TCAP + pos] = (u32)p;
      }
    }
    if(p1){
      if(e1 > thr1){
        u32 pos = atomicAdd(&ws[OCNTA+1], 1u);
        if(pos < ACAP) listA[ACAP + pos] = ((u64)e1<<32) | (u32)(~(u32)p);
      } else if(e1 == thr1){
        u32 pos = atomicAdd(&ws[OCNTT + NSHARD + sh], 1u);
        if(pos < TCAP) ws[OLISTT + (NSHARD+sh)*TCAP + pos] = (u32)p;
      }
    }
  }
}

__global__ __launch_bounds__(1024) void finalize_kernel(
    u32* __restrict__ ws, const u32* __restrict__ szm, const u16* __restrict__ offm,
    const u16* __restrict__ orig, u16* __restrict__ out){
  __shared__ u64 keys[ACAP];
  __shared__ u32 h2[2048];
  __shared__ u32 s1[1024];
  __shared__ u32 wbits[64];
  __shared__ u32 sel[ACAP];
  __shared__ int Bsh, K1sh, selc, bndc, nselsh;
  __shared__ float oval[TOPK]; __shared__ int oidx[TOPK];
  __shared__ float nval[TOPK]; __shared__ int nidx[TOPK];
  __shared__ float cbox[TOPK][4]; __shared__ float cscore[TOPK]; __shared__ float area[TOPK];
  __shared__ int sup[TOPK]; __shared__ int slotv[TOPK];
  __shared__ int nkeep_s, meanr, meanc;
  int tid = threadIdx.x;
  const u64* listA = (const u64*)(ws + OLISTA);

  for(int ch=0; ch<2; ++ch){
    int nA = (int)ws[OCNTA+ch]; if(nA > ACAP) nA = ACAP;
    u32 thr = (u32)((const int*)ws)[OTHR+ch];
    float tval = up16(dec16(thr));
    // sort listA desc (pad 0; real keys have enc>=0x8000 so pad sinks)
    if(tid < ACAP) keys[tid] = (tid < nA) ? listA[ch*ACAP + tid] : 0ull;
    __syncthreads();
    for(int k=2;k<=ACAP;k<<=1)
      for(int j=k>>1;j>0;j>>=1){
        if(tid < ACAP){
          int ixj = tid ^ j;
          if(ixj > tid){
            u64 a = keys[tid], b = keys[ixj];
            bool up = ((tid & k) == 0);
            if(up ? (a < b) : (a > b)){ keys[tid] = b; keys[ixj] = a; }
          }
        }
        __syncthreads();
      }
    int nA100 = nA < TOPK ? nA : TOPK;
    int need = TOPK - nA100;
    need = need < 0 ? 0 : need;

    // ---- exact smallest-`need` indices among ties ----
    for(int j=tid;j<2048;j+=1024) h2[j]=0u;
    if(tid < 64) wbits[tid] = 0u;
    if(tid == 0){ Bsh = 0x7FFFFFFF; K1sh = 0; selc = 0; bndc = 0; nselsh = 0; }
    __syncthreads();
    if(need > 0){
      for(int s=0;s<NSHARD;++s){
        int ns = (int)ws[OCNTT + ch*NSHARD + s]; if(ns > TCAP) ns = TCAP;
        const u32* seg = ws + OLISTT + (ch*NSHARD + s)*TCAP;
        for(int i=tid;i<ns;i+=1024) atomicAdd(&h2[seg[i]>>11], 1u);
      }
      __syncthreads();
      s1[tid] = h2[2*tid] + h2[2*tid+1];
      __syncthreads();
      for(int off=1;off<1024;off<<=1){
        u32 v = (tid >= off) ? s1[tid-off] : 0u;
        __syncthreads();
        s1[tid] += v;
        __syncthreads();
      }
      {
        u32 S = s1[tid];
        u32 cum1 = S;                       // inclusive cum of bin 2t+1
        u32 cum0 = S - h2[2*tid+1];         // inclusive cum of bin 2t
        if(cum0 >= (u32)need && h2[2*tid])   atomicMin(&Bsh, 2*tid);
        if(cum1 >= (u32)need && h2[2*tid+1]) atomicMin(&Bsh, 2*tid+1);
      }
      __syncthreads();
      {
        int B = Bsh;
        if(B < 2048 && (B>>1) == tid){
          u32 S = s1[tid];
          u32 cum = (B & 1) ? S : (S - h2[2*tid+1]);
          K1sh = (int)(cum - h2[B]);
        }
      }
      __syncthreads();
      int B = Bsh;
      for(int s=0;s<NSHARD;++s){
        int ns = (int)ws[OCNTT + ch*NSHARD + s]; if(ns > TCAP) ns = TCAP;
        const u32* seg = ws + OLISTT + (ch*NSHARD + s)*TCAP;
        for(int i=tid;i<ns;i+=1024){
          u32 idx = seg[i];
          int b = (int)(idx>>11);
          if(b < B){
            int pos = atomicAdd(&selc, 1);
            if(pos < ACAP) sel[pos] = idx;
          } else if(b == B){
            atomicOr(&wbits[(idx&2047)>>5], 1u<<(idx&31));
          }
        }
      }
      __syncthreads();
      if(tid == 0){
        int k1 = selc;                     // == K1sh (unordered gather count)
        int rem = need - k1;
        int cnt = 0;
        int B2 = Bsh;
        for(int wi=0; wi<64 && rem>0; ++wi){
          u32 bits = wbits[wi];
          while(bits && rem>0){
            int l = __ffs(bits) - 1;
            bits &= bits - 1;
            if(k1 + cnt < ACAP) sel[k1 + cnt] = ((u32)B2<<11) | ((u32)wi<<5) | (u32)l;
            ++cnt; --rem;
          }
        }
        nselsh = k1 + cnt;
      }
      __syncthreads();
      // sort sel ascending (pad 0xFFFFFFFF)
      if(tid < ACAP && tid >= nselsh) sel[tid] = 0xFFFFFFFFu;
      __syncthreads();
      for(int k=2;k<=ACAP;k<<=1)
        for(int j=k>>1;j>0;j>>=1){
          if(tid < ACAP){
            int ixj = tid ^ j;
            if(ixj > tid){
              u32 a = sel[tid], b = sel[ixj];
              bool up = ((tid & k) == 0);
              if(up ? (a > b) : (a < b)){ sel[tid] = b; sel[ixj] = a; }
            }
          }
          __syncthreads();
        }
    }
    // assemble per-channel top-100 (value desc, index asc on ties == lax.top_k)
    if(tid < TOPK){
      float v; int ii;
      if(tid < nA100){
        u64 key = keys[tid];
        v = up16(dec16((u32)(key>>32)));
        ii = (int)(~(u32)(key & 0xFFFFFFFFu));
      } else if(tid - nA100 < nselsh){
        v = tval; ii = (int)sel[tid - nA100];
      } else { v = 0.0f; ii = 0; }
      if(ch == 0){ oval[tid] = v; oidx[tid] = ii; }
      else       { nval[tid] = v; nidx[tid] = ii; }
    }
    __syncthreads();
  }

  float ry = up16(orig[0]) / 1536.0f;
  float rx = up16(orig[1]) / 1536.0f;

  if(tid == 0){
    int c = 0, sr = 0, sc = 0;
    for(int j=0;j<TOPK;++j)
      if(nval[j] > 0.5f){ c++; sr += nidx[j] / IW; sc += nidx[j] % IW; }
    if(c < 1) c = 1;
    meanr = sr / c; meanc = sc / c;
  }
  if(tid < TOPK) out[610 + tid] = f2bf(nval[tid] > 0.5f ? nval[tid] : -1.0f);

  if(tid < TOPK){
    int idx = oidx[tid];
    int r = idx / IW, c = idx - r*IW;
    float score = oval[tid];
    u32 sz = szm[idx];
    float sy = up16(sz), sx = up16(sz>>16);
    float cy = (float)r, cx = (float)c;
    float tly = fmaxf(cy - sy*0.5f, 0.0f);
    float tlx = fmaxf(cx - sx*0.5f, 0.0f);
    float bry = fminf(cy + sy*0.5f, 1535.0f);
    float brx = fminf(cx + sx*0.5f, 1535.0f);
    bool mk = score > 0.3f;
    float b0 = mk ? tly*ry : -1.0f;
    float b1 = mk ? tlx*rx : -1.0f;
    float b2 = mk ? bry*ry : -1.0f;
    float b3 = mk ? brx*rx : -1.0f;
    cbox[tid][0]=b0; cbox[tid][1]=b1; cbox[tid][2]=b2; cbox[tid][3]=b3;
    cscore[tid] = mk ? score : -1.0f;
    area[tid] = fmaxf(b2-b0,0.0f) * fmaxf(b3-b1,0.0f);
    sup[tid] = 0;
  }
  __syncthreads();

  for(int i=0;i<TOPK;++i){
    if(sup[i]==0 && tid>i && tid<TOPK){
      float iy1 = fmaxf(cbox[i][0], cbox[tid][0]);
      float ix1 = fmaxf(cbox[i][1], cbox[tid][1]);
      float iy2 = fminf(cbox[i][2], cbox[tid][2]);
      float ix2 = fminf(cbox[i][3], cbox[tid][3]);
      float inter = fmaxf(iy2-iy1,0.0f) * fmaxf(ix2-ix1,0.0f);
      float uni = (area[i] + area[tid]) - inter;
      if(inter / fmaxf(uni, 1e-8f) > 0.5f) sup[tid] = 1;
    }
    __syncthreads();
  }

  if(tid == 0){
    int k = 0;
    for(int i=0;i<TOPK;++i) if(!sup[i]) slotv[k++] = i;
    nkeep_s = k;
    for(int i=0;i<TOPK;++i) if(sup[i]) slotv[k++] = i;
  }
  __syncthreads();

  if(tid < TOPK){
    int s = slotv[tid];
    bool ks = (tid < nkeep_s);
    u16 row[6];
    if(ks){
      for(int d=0;d<4;++d){
        float v = cbox[s][d];
        row[d] = (v == -1.0f || v == 0.0f) ? (u16)BF_INF16 : f2bf(v);
      }
      row[4] = f2bf(cscore[s]);
    } else {
      for(int d=0;d<4;++d) row[d] = (u16)BF_INF16;
      row[4] = 0;
    }
    row[5] = 0;
    for(int d=0;d<6;++d) out[tid*6 + d] = row[d];
  }

  if(tid == 0){
    float lfy = (float)meanr, lfx = (float)meanc;
    out[600] = f2bf(lfy * ry);
    out[601] = f2bf(lfx * rx);
    const u16* op = offm + ((size_t)meanr*IW + meanc)*8;
    for(int p=0;p<4;++p){
      out[602 + p*2 + 0] = f2bf((lfy - up16(op[p*2+0])) * ry);
      out[602 + p*2 + 1] = f2bf((lfx - up16(op[p*2+1])) * rx);
    }
  }
}

extern "C" void kernel_launch(void* const* d_in, const int* in_sizes, int n_in,
                              void* d_out, int out_size, void* d_ws, size_t ws_size,
                              hipStream_t stream) {
  const u32* heat = (const u32*)d_in[0];   // bf16 pairs (ch1<<16|ch0) per pixel
  const u16* offm = (const u16*)d_in[1];   // bf16 (1,1536,1536,8)
  const u32* szm  = (const u32*)d_in[2];   // bf16 pairs per pixel
  const u16* orig = (const u16*)d_in[3];   // bf16 (1,2)
  u16* out = (u16*)d_out;
  u32* ws = (u32*)d_ws;

  zero_kernel<<<1, 256, 0, stream>>>(ws);
  hist_msd_kernel<<<NBLK, 1024, 0, stream>>>(heat, ws);
  sel_msd_kernel<<<1, 512, 0, stream>>>(ws);
  hist_lsd_kernel<<<NBLK, 1024, 0, stream>>>(heat, ws);
  sel_lsd_kernel<<<1, 512, 0, stream>>>(ws);
  collect_kernel<<<NBLK, 1024, 0, stream>>>(heat, ws);
  finalize_kernel<<<1, 1024, 0, stream>>>(ws, szm, offm, orig, out);
}

// Round 4
// 232.789 us; speedup vs baseline: 1.5912x; 1.5912x over previous
//
#include <hip/hip_runtime.h>
#include <cstdint>

#define IW 1536
#define IH 1536
#define TOPK 100
#define CAPP 327680   // peak-list cap per channel (expected ~262k, >25 sigma margin)
#define CAPB 128      // >thr list cap (provably <=99 entries)
#define CAPT 8192     // tie list cap per channel (expected ~4600)
#define BF_INF16 0x7F7Fu  // bf16 max-finite stand-in for +inf (inf-inf=NaN in comparator)

typedef unsigned u32; typedef unsigned long long u64; typedef unsigned short u16;

// ---- workspace layout (u32 offsets); total ~2.7 MB ----
#define OH1   0       // 512: MSD hist (2ch x 256), global-atomic accumulated
#define OH2   512     // 512: LSD hist
#define OSEL  1024    // D0,D1,Shi0,Shi1,thr0,thr1
#define OCNT  1032    // cntP0,cntP1,cntB0,cntB1,cntT0,cntT1
#define OLB   1040    // 2*128 u64 (byte 4160, 8-aligned)
#define OLT   1552    // 2*8192 u32 tie lists
#define OPK   17936   // 2*CAPP u32 peak index lists

__device__ __forceinline__ u32 enc16(u32 b){ b &= 0xFFFFu; return (b & 0x8000u) ? ((~b)&0xFFFFu) : (b|0x8000u); }
__device__ __forceinline__ u32 dec16(u32 e){ return (e & 0x8000u) ? (e^0x8000u) : ((~e)&0xFFFFu); }
__device__ __forceinline__ float up16(u32 b){ return __uint_as_float((b&0xFFFFu)<<16); }
__device__ __forceinline__ u16 f2bf(float f){ u32 u=__float_as_uint(f); return (u16)((u + 0x7FFFu + ((u>>16)&1u))>>16); }

__global__ void zero_kernel(u32* __restrict__ ws){
  int i = threadIdx.x;
  for(int j=i;j<1040;j+=1024) ws[j]=0u;   // hists + sel + counters
}

// ONE image pass: peak detect (raw bf16 code compare; valid for non-negative
// heatmap), peak-index list append (ballot-aggregated), MSD histogram.
__global__ __launch_bounds__(1024) void scan_kernel(const u32* __restrict__ hm, u32* __restrict__ ws){
  __shared__ u32 lh[512];
  __shared__ u32 lbuf[2][1600];
  __shared__ u32 lcnt[2], lbase[2];
  int tid = threadIdx.x, lane = tid & 63;
  for(int i=tid;i<512;i+=1024) lh[i]=0u;
  if(tid<2) lcnt[tid]=0u;
  __syncthreads();

  int p = (blockIdx.x*1024 + tid)*4;      // 4 consecutive pixels, never crosses a row
  int y = p / IW, x = p - y*IW;
  const u32* R1 = hm + y*IW;
  const u32* R0 = y ? R1 - IW : R1;                 // clamped rows: safe w/ >= test
  const u32* R2 = (y < IH-1) ? R1 + IW : R1;
  uint4 c0 = *(const uint4*)(R0+x), c1 = *(const uint4*)(R1+x), c2 = *(const uint4*)(R2+x);
  int xl = x ? x-1 : 0, xr = (x+4 < IW) ? x+4 : IW-1;
  u32 a0[6] = {R0[xl], c0.x, c0.y, c0.z, c0.w, R0[xr]};
  u32 a1[6] = {R1[xl], c1.x, c1.y, c1.z, c1.w, R1[xr]};
  u32 a2[6] = {R2[xl], c2.x, c2.y, c2.z, c2.w, R2[xr]};

  #pragma unroll
  for(int j=0;j<4;++j){
    u32 c = a1[j+1];
    u32 cl = c & 0xFFFFu, chv = c >> 16;
    u32 m0=0u, m1=0u;
    #pragma unroll
    for(int d=0;d<3;++d){
      u32 n0=a0[j+d], n2=a2[j+d];
      u32 t;
      t=n0&0xFFFFu; m0=t>m0?t:m0;  t=n0>>16; m1=t>m1?t:m1;
      t=n2&0xFFFFu; m0=t>m0?t:m0;  t=n2>>16; m1=t>m1?t:m1;
    }
    { u32 n=a1[j]; u32 t=n&0xFFFFu; m0=t>m0?t:m0; t=n>>16; m1=t>m1?t:m1; }
    { u32 n=a1[j+2]; u32 t=n&0xFFFFu; m0=t>m0?t:m0; t=n>>16; m1=t>m1?t:m1; }
    bool p0 = (cl >= m0), p1 = (chv >= m1);

    u64 mk0 = __ballot(p0);
    if(mk0){
      u32 cntw = __popcll(mk0), b;
      if(lane==0) b = atomicAdd(&lcnt[0], cntw);
      b = __shfl(b, 0);
      if(p0){
        u32 pos = b + __popcll(mk0 & ((1ull<<lane)-1ull));
        if(pos < 1600) lbuf[0][pos] = (u32)(p+j);
      }
    }
    u64 mk1 = __ballot(p1);
    if(mk1){
      u32 cntw = __popcll(mk1), b;
      if(lane==0) b = atomicAdd(&lcnt[1], cntw);
      b = __shfl(b, 0);
      if(p1){
        u32 pos = b + __popcll(mk1 & ((1ull<<lane)-1ull));
        if(pos < 1600) lbuf[1][pos] = (u32)(p+j);
      }
    }
    if(p0) atomicAdd(&lh[enc16(cl)>>8], 1u);
    if(p1) atomicAdd(&lh[256 + (enc16(chv)>>8)], 1u);
  }
  __syncthreads();
  if(tid < 2){
    u32 n = lcnt[tid]; if(n > 1600) n = 1600;
    lcnt[tid] = n;
    lbase[tid] = atomicAdd(&ws[OCNT+tid], n);
  }
  __syncthreads();
  for(int ch=0;ch<2;++ch){
    u32 n = lcnt[ch], base = lbase[ch];
    for(u32 i=tid;i<n;i+=1024){
      u32 g = base + i;
      if(g < CAPP) ws[OPK + ch*CAPP + g] = lbuf[ch][i];
    }
  }
  for(int i=tid;i<512;i+=1024) if(lh[i]) atomicAdd(&ws[OH1+i], lh[i]);
}

__global__ void sel_msd_kernel(u32* __restrict__ ws){
  __shared__ u32 h[512];
  int t = threadIdx.x;
  h[t] = ws[OH1+t];
  __syncthreads();
  if(t < 2){
    const u32* hh = h + t*256;
    u32 above = 0; int D = 0;
    for(int b=255;b>=1;--b){
      if(above + hh[b] >= (u32)TOPK){ D = b; break; }
      above += hh[b];
    }
    ws[OSEL+t] = (u32)D;
    ws[OSEL+2+t] = above;     // count strictly above digit D
  }
}

// LSD histogram over peak list entries whose MSD digit == D
__global__ __launch_bounds__(1024) void lsd_kernel(const u32* __restrict__ hm, u32* __restrict__ ws){
  __shared__ u32 lh[512];
  int tid = threadIdx.x;
  for(int i=tid;i<512;i+=1024) lh[i]=0u;
  __syncthreads();
  int D0 = (int)ws[OSEL], D1 = (int)ws[OSEL+1];
  for(int ch=0;ch<2;++ch){
    u32 n = ws[OCNT+ch]; if(n > CAPP) n = CAPP;
    int D = ch ? D1 : D0;
    for(u32 i = blockIdx.x*1024 + tid; i < n; i += gridDim.x*1024){
      u32 idx = ws[OPK + ch*CAPP + i];
      u32 e = enc16(hm[idx] >> (16*ch));
      if((int)(e>>8) == D) atomicAdd(&lh[ch*256 + (e&255)], 1u);
    }
  }
  __syncthreads();
  for(int i=tid;i<512;i+=1024) if(lh[i]) atomicAdd(&ws[OH2+i], lh[i]);
}

__global__ void sel_lsd_kernel(u32* __restrict__ ws){
  __shared__ u32 h[512];
  int t = threadIdx.x;
  h[t] = ws[OH2+t];
  __syncthreads();
  if(t < 2){
    int D = (int)ws[OSEL+t];
    int need2 = TOPK - (int)ws[OSEL+2+t];   // in [1,100]
    const u32* hh = h + t*256;
    u32 above = 0; int L = 0;
    for(int b=255;b>=1;--b){
      if((int)(above + hh[b]) >= need2){ L = b; break; }
      above += hh[b];
    }
    ws[OSEL+4+t] = (u32)((D<<8) | L);       // full 16-bit enc threshold
  }
}

// collect: enc>thr -> listB (u64 keys, <=99); enc==thr -> contiguous tie list
__global__ __launch_bounds__(1024) void collect_kernel(const u32* __restrict__ hm, u32* __restrict__ ws){
  __shared__ u32 tbuf[2][2048];
  __shared__ u32 tcnt[2], tbase[2];
  int tid = threadIdx.x, lane = tid & 63;
  if(tid<2) tcnt[tid]=0u;
  __syncthreads();
  u32 thr0 = ws[OSEL+4], thr1 = ws[OSEL+5];
  u64* listB = (u64*)(ws + OLB);
  u32 total = gridDim.x*1024;
  for(int ch=0;ch<2;++ch){
    u32 n = ws[OCNT+ch]; if(n > CAPP) n = CAPP;
    u32 thr = ch ? thr1 : thr0;
    for(u32 base = blockIdx.x*1024; base < n; base += total){
      u32 i = base + tid;
      bool act = (i < n);
      u32 idx = 0, e = 0;
      if(act){ idx = ws[OPK + ch*CAPP + i]; e = enc16(hm[idx] >> (16*ch)); }
      if(act && e > thr){
        u32 pos = atomicAdd(&ws[OCNT+2+ch], 1u);
        if(pos < CAPB) listB[ch*CAPB + pos] = ((u64)e<<32) | (u32)(~idx);
      }
      bool isT = act && (e == thr);
      u64 mk = __ballot(isT);
      if(mk){
        u32 cntw = __popcll(mk), b;
        if(lane==0) b = atomicAdd(&tcnt[ch], cntw);
        b = __shfl(b, 0);
        if(isT){
          u32 pos = b + __popcll(mk & ((1ull<<lane)-1ull));
          if(pos < 2048) tbuf[ch][pos] = idx;
        }
      }
    }
  }
  __syncthreads();
  if(tid < 2){
    u32 c = tcnt[tid]; if(c > 2048) c = 2048;
    tcnt[tid] = c;
    tbase[tid] = atomicAdd(&ws[OCNT+4+tid], c);
  }
  __syncthreads();
  for(int ch=0;ch<2;++ch)
    for(u32 i=tid;i<tcnt[ch];i+=1024){
      u32 g = tbase[ch] + i;
      if(g < CAPT) ws[OLT + ch*CAPT + g] = tbuf[ch][i];
    }
}

__global__ __launch_bounds__(1024) void finalize_kernel(
    u32* __restrict__ ws, const u32* __restrict__ szm, const u16* __restrict__ offm,
    const u16* __restrict__ orig, u16* __restrict__ out){
  __shared__ u64 keys[CAPB];
  __shared__ u32 h2[2048];
  __shared__ u32 s1[1024];
  __shared__ u32 wbits[64];
  __shared__ u32 sel[CAPB];
  __shared__ int Bsh, selc, nselsh;
  __shared__ float oval[TOPK]; __shared__ int oidx[TOPK];
  __shared__ float nval[TOPK]; __shared__ int nidx[TOPK];
  __shared__ float cbox[TOPK][4]; __shared__ float cscore[TOPK]; __shared__ float area[TOPK];
  __shared__ int sup[TOPK]; __shared__ int slotv[TOPK];
  __shared__ int nkeep_s, meanr, meanc;
  int tid = threadIdx.x;
  const u64* listB = (const u64*)(ws + OLB);

  for(int ch=0; ch<2; ++ch){
    int nB = (int)ws[OCNT+2+ch]; if(nB > CAPB) nB = CAPB;
    u32 thr = ws[OSEL+4+ch];
    float tval = up16(dec16(thr));
    if(tid < CAPB) keys[tid] = (tid < nB) ? listB[ch*CAPB + tid] : 0ull;
    __syncthreads();
    for(int k=2;k<=CAPB;k<<=1)
      for(int j=k>>1;j>0;j>>=1){
        if(tid < CAPB){
          int ixj = tid ^ j;
          if(ixj > tid){
            u64 a = keys[tid], b = keys[ixj];
            bool up = ((tid & k) == 0);
            if(up ? (a < b) : (a > b)){ keys[tid] = b; keys[ixj] = a; }
          }
        }
        __syncthreads();
      }
    int nA100 = nB < TOPK ? nB : TOPK;
    int need = TOPK - nA100;

    for(int j=tid;j<2048;j+=1024) h2[j]=0u;
    if(tid < 64) wbits[tid] = 0u;
    if(tid == 0){ Bsh = 0x7FFFFFFF; selc = 0; nselsh = 0; }
    __syncthreads();
    if(need > 0){
      int nT = (int)ws[OCNT+4+ch]; if(nT > CAPT) nT = CAPT;
      const u32* seg = ws + OLT + ch*CAPT;
      for(int i=tid;i<nT;i+=1024) atomicAdd(&h2[seg[i]>>11], 1u);
      __syncthreads();
      s1[tid] = h2[2*tid] + h2[2*tid+1];
      __syncthreads();
      for(int off=1;off<1024;off<<=1){
        u32 v = (tid >= off) ? s1[tid-off] : 0u;
        __syncthreads();
        s1[tid] += v;
        __syncthreads();
      }
      {
        u32 S = s1[tid];
        u32 cum1 = S;
        u32 cum0 = S - h2[2*tid+1];
        if(cum0 >= (u32)need && h2[2*tid])   atomicMin(&Bsh, 2*tid);
        if(cum1 >= (u32)need && h2[2*tid+1]) atomicMin(&Bsh, 2*tid+1);
      }
      __syncthreads();
      int B = Bsh;
      for(int i=tid;i<nT;i+=1024){
        u32 idx = seg[i];
        int b = (int)(idx>>11);
        if(b < B){
          int pos = atomicAdd(&selc, 1);
          if(pos < CAPB) sel[pos] = idx;
        } else if(b == B){
          atomicOr(&wbits[(idx&2047)>>5], 1u<<(idx&31));
        }
      }
      __syncthreads();
      if(tid == 0){
        int k1 = selc;
        int rem = need - k1;
        int cnt = 0;
        for(int wi=0; wi<64 && rem>0; ++wi){
          u32 bits = wbits[wi];
          while(bits && rem>0){
            int l = __ffs(bits) - 1;
            bits &= bits - 1;
            if(k1 + cnt < CAPB) sel[k1 + cnt] = ((u32)B<<11) | ((u32)wi<<5) | (u32)l;
            ++cnt; --rem;
          }
        }
        nselsh = k1 + cnt;
      }
      __syncthreads();
      if(tid < CAPB && tid >= nselsh) sel[tid] = 0xFFFFFFFFu;
      __syncthreads();
      for(int k=2;k<=CAPB;k<<=1)
        for(int j=k>>1;j>0;j>>=1){
          if(tid < CAPB){
            int ixj = tid ^ j;
            if(ixj > tid){
              u32 a = sel[tid], b = sel[ixj];
              bool up = ((tid & k) == 0);
              if(up ? (a > b) : (a < b)){ sel[tid] = b; sel[ixj] = a; }
            }
          }
          __syncthreads();
        }
    }
    if(tid < TOPK){
      float v; int ii;
      if(tid < nA100){
        u64 key = keys[tid];
        v = up16(dec16((u32)(key>>32)));
        ii = (int)(~(u32)(key & 0xFFFFFFFFu));
      } else if(tid - nA100 < nselsh){
        v = tval; ii = (int)sel[tid - nA100];
      } else { v = 0.0f; ii = 0; }
      if(ch == 0){ oval[tid] = v; oidx[tid] = ii; }
      else       { nval[tid] = v; nidx[tid] = ii; }
    }
    __syncthreads();
  }

  float ry = up16(orig[0]) / 1536.0f;
  float rx = up16(orig[1]) / 1536.0f;

  if(tid == 0){
    int c = 0, sr = 0, sc = 0;
    for(int j=0;j<TOPK;++j)
      if(nval[j] > 0.5f){ c++; sr += nidx[j] / IW; sc += nidx[j] % IW; }
    if(c < 1) c = 1;
    meanr = sr / c; meanc = sc / c;
  }
  if(tid < TOPK) out[610 + tid] = f2bf(nval[tid] > 0.5f ? nval[tid] : -1.0f);

  if(tid < TOPK){
    int idx = oidx[tid];
    int r = idx / IW, c = idx - r*IW;
    float score = oval[tid];
    u32 sz = szm[idx];
    float sy = up16(sz), sx = up16(sz>>16);
    float cy = (float)r, cx = (float)c;
    float tly = fmaxf(cy - sy*0.5f, 0.0f);
    float tlx = fmaxf(cx - sx*0.5f, 0.0f);
    float bry = fminf(cy + sy*0.5f, 1535.0f);
    float brx = fminf(cx + sx*0.5f, 1535.0f);
    bool mk = score > 0.3f;
    float b0 = mk ? tly*ry : -1.0f;
    float b1 = mk ? tlx*rx : -1.0f;
    float b2 = mk ? bry*ry : -1.0f;
    float b3 = mk ? brx*rx : -1.0f;
    cbox[tid][0]=b0; cbox[tid][1]=b1; cbox[tid][2]=b2; cbox[tid][3]=b3;
    cscore[tid] = mk ? score : -1.0f;
    area[tid] = fmaxf(b2-b0,0.0f) * fmaxf(b3-b1,0.0f);
    sup[tid] = 0;
  }
  __syncthreads();

  for(int i=0;i<TOPK;++i){
    if(sup[i]==0 && tid>i && tid<TOPK){
      float iy1 = fmaxf(cbox[i][0], cbox[tid][0]);
      float ix1 = fmaxf(cbox[i][1], cbox[tid][1]);
      float iy2 = fminf(cbox[i][2], cbox[tid][2]);
      float ix2 = fminf(cbox[i][3], cbox[tid][3]);
      float inter = fmaxf(iy2-iy1,0.0f) * fmaxf(ix2-ix1,0.0f);
      float uni = (area[i] + area[tid]) - inter;
      if(inter / fmaxf(uni, 1e-8f) > 0.5f) sup[tid] = 1;
    }
    __syncthreads();
  }

  if(tid == 0){
    int k = 0;
    for(int i=0;i<TOPK;++i) if(!sup[i]) slotv[k++] = i;
    nkeep_s = k;
    for(int i=0;i<TOPK;++i) if(sup[i]) slotv[k++] = i;
  }
  __syncthreads();

  if(tid < TOPK){
    int s = slotv[tid];
    bool ks = (tid < nkeep_s);
    u16 row[6];
    if(ks){
      for(int d=0;d<4;++d){
        float v = cbox[s][d];
        row[d] = (v == -1.0f || v == 0.0f) ? (u16)BF_INF16 : f2bf(v);
      }
      row[4] = f2bf(cscore[s]);
    } else {
      for(int d=0;d<4;++d) row[d] = (u16)BF_INF16;
      row[4] = 0;
    }
    row[5] = 0;
    for(int d=0;d<6;++d) out[tid*6 + d] = row[d];
  }

  if(tid == 0){
    float lfy = (float)meanr, lfx = (float)meanc;
    out[600] = f2bf(lfy * ry);
    out[601] = f2bf(lfx * rx);
    const u16* op = offm + ((size_t)meanr*IW + meanc)*8;
    for(int p=0;p<4;++p){
      out[602 + p*2 + 0] = f2bf((lfy - up16(op[p*2+0])) * ry);
      out[602 + p*2 + 1] = f2bf((lfx - up16(op[p*2+1])) * rx);
    }
  }
}

extern "C" void kernel_launch(void* const* d_in, const int* in_sizes, int n_in,
                              void* d_out, int out_size, void* d_ws, size_t ws_size,
                              hipStream_t stream) {
  const u32* heat = (const u32*)d_in[0];   // bf16 pairs (ch1<<16|ch0) per pixel
  const u16* offm = (const u16*)d_in[1];
  const u32* szm  = (const u32*)d_in[2];
  const u16* orig = (const u16*)d_in[3];
  u16* out = (u16*)d_out;
  u32* ws = (u32*)d_ws;

  zero_kernel<<<1, 1024, 0, stream>>>(ws);
  scan_kernel<<<576, 1024, 0, stream>>>(heat, ws);
  sel_msd_kernel<<<1, 512, 0, stream>>>(ws);
  lsd_kernel<<<128, 1024, 0, stream>>>(heat, ws);
  sel_lsd_kernel<<<1, 512, 0, stream>>>(ws);
  collect_kernel<<<128, 1024, 0, stream>>>(heat, ws);
  finalize_kernel<<<1, 1024, 0, stream>>>(ws, szm, offm, orig, out);
}

// Round 5
// 195.883 us; speedup vs baseline: 1.8910x; 1.1884x over previous
//
#include <hip/hip_runtime.h>
#include <cstdint>

#define IW 1536
#define IH 1536
#define TOPK 100
#define CAPP 327680   // peak-list cap per channel (expected ~262k)
#define CAPB 128      // >thr list cap (provably <=99 entries)
#define CAPT 8192     // tie list cap per channel (expected ~4600)
#define BF_INF16 0x7F7Fu  // bf16 max-finite stand-in for +inf (inf-inf=NaN in comparator)

typedef unsigned u32; typedef unsigned long long u64; typedef unsigned short u16;

// ---- workspace layout (u32 offsets); total ~2.7 MB ----
#define OH1   0       // 512: MSD hist (2ch x 256)
#define OH2   512     // 512: LSD hist
#define OSEL  1024    // D0,D1,Shi0,Shi1,thr0,thr1
#define OCNT  1032    // cntP0,cntP1,cntB0,cntB1,cntT0,cntT1
#define OLB   1040    // 2*128 u64 (byte 4160, 8-aligned)
#define OLT   1552    // 2*8192 u32 tie lists
#define OPK   17936   // 2*CAPP u32 peak index lists

__device__ __forceinline__ u32 enc16(u32 b){ b &= 0xFFFFu; return (b & 0x8000u) ? ((~b)&0xFFFFu) : (b|0x8000u); }
__device__ __forceinline__ u32 dec16(u32 e){ return (e & 0x8000u) ? (e^0x8000u) : ((~e)&0xFFFFu); }
__device__ __forceinline__ float up16(u32 b){ return __uint_as_float((b&0xFFFFu)<<16); }
__device__ __forceinline__ u16 f2bf(float f){ u32 u=__float_as_uint(f); return (u16)((u + 0x7FFFu + ((u>>16)&1u))>>16); }

// ONE image pass: peak detect (raw bf16 code compare; valid for non-negative
// heatmap), peak-index list append (ballot-aggregated), MSD histogram.
__global__ __launch_bounds__(1024) void scan_kernel(const u32* __restrict__ hm, u32* __restrict__ ws){
  __shared__ u32 lh[512];
  __shared__ u32 lbuf[2][1600];
  __shared__ u32 lcnt[2], lbase[2];
  int tid = threadIdx.x, lane = tid & 63;
  for(int i=tid;i<512;i+=1024) lh[i]=0u;
  if(tid<2) lcnt[tid]=0u;
  __syncthreads();

  int p = (blockIdx.x*1024 + tid)*4;      // 4 consecutive pixels, never crosses a row
  int y = p / IW, x = p - y*IW;
  const u32* R1 = hm + y*IW;
  const u32* R0 = y ? R1 - IW : R1;                 // clamped rows: safe w/ >= test
  const u32* R2 = (y < IH-1) ? R1 + IW : R1;
  uint4 c0 = *(const uint4*)(R0+x), c1 = *(const uint4*)(R1+x), c2 = *(const uint4*)(R2+x);
  int xl = x ? x-1 : 0, xr = (x+4 < IW) ? x+4 : IW-1;
  u32 a0[6] = {R0[xl], c0.x, c0.y, c0.z, c0.w, R0[xr]};
  u32 a1[6] = {R1[xl], c1.x, c1.y, c1.z, c1.w, R1[xr]};
  u32 a2[6] = {R2[xl], c2.x, c2.y, c2.z, c2.w, R2[xr]};

  #pragma unroll
  for(int j=0;j<4;++j){
    u32 c = a1[j+1];
    u32 cl = c & 0xFFFFu, chv = c >> 16;
    u32 m0=0u, m1=0u;
    #pragma unroll
    for(int d=0;d<3;++d){
      u32 n0=a0[j+d], n2=a2[j+d];
      u32 t;
      t=n0&0xFFFFu; m0=t>m0?t:m0;  t=n0>>16; m1=t>m1?t:m1;
      t=n2&0xFFFFu; m0=t>m0?t:m0;  t=n2>>16; m1=t>m1?t:m1;
    }
    { u32 n=a1[j]; u32 t=n&0xFFFFu; m0=t>m0?t:m0; t=n>>16; m1=t>m1?t:m1; }
    { u32 n=a1[j+2]; u32 t=n&0xFFFFu; m0=t>m0?t:m0; t=n>>16; m1=t>m1?t:m1; }
    bool p0 = (cl >= m0), p1 = (chv >= m1);

    u64 mk0 = __ballot(p0);
    if(mk0){
      u32 cntw = __popcll(mk0), b;
      if(lane==0) b = atomicAdd(&lcnt[0], cntw);
      b = __shfl(b, 0);
      if(p0){
        u32 pos = b + __popcll(mk0 & ((1ull<<lane)-1ull));
        if(pos < 1600) lbuf[0][pos] = (u32)(p+j);
      }
    }
    u64 mk1 = __ballot(p1);
    if(mk1){
      u32 cntw = __popcll(mk1), b;
      if(lane==0) b = atomicAdd(&lcnt[1], cntw);
      b = __shfl(b, 0);
      if(p1){
        u32 pos = b + __popcll(mk1 & ((1ull<<lane)-1ull));
        if(pos < 1600) lbuf[1][pos] = (u32)(p+j);
      }
    }
    if(p0) atomicAdd(&lh[enc16(cl)>>8], 1u);
    if(p1) atomicAdd(&lh[256 + (enc16(chv)>>8)], 1u);
  }
  __syncthreads();
  if(tid < 2){
    u32 n = lcnt[tid]; if(n > 1600) n = 1600;
    lcnt[tid] = n;
    lbase[tid] = atomicAdd(&ws[OCNT+tid], n);
  }
  __syncthreads();
  for(int ch=0;ch<2;++ch){
    u32 n = lcnt[ch], base = lbase[ch];
    for(u32 i=tid;i<n;i+=1024){
      u32 g = base + i;
      if(g < CAPP) ws[OPK + ch*CAPP + g] = lbuf[ch][i];
    }
  }
  for(int i=tid;i<512;i+=1024) if(lh[i]) atomicAdd(&ws[OH1+i], lh[i]);
}

__global__ void sel_msd_kernel(u32* __restrict__ ws){
  __shared__ u32 h[512];
  int t = threadIdx.x;
  h[t] = ws[OH1+t];
  __syncthreads();
  if(t < 2){
    const u32* hh = h + t*256;
    u32 above = 0; int D = 0;
    for(int b=255;b>=1;--b){
      if(above + hh[b] >= (u32)TOPK){ D = b; break; }
      above += hh[b];
    }
    ws[OSEL+t] = (u32)D;
    ws[OSEL+2+t] = above;     // count strictly above digit D
  }
}

// LSD histogram over peak list entries whose MSD digit == D
__global__ __launch_bounds__(1024) void lsd_kernel(const u32* __restrict__ hm, u32* __restrict__ ws){
  __shared__ u32 lh[512];
  int tid = threadIdx.x;
  for(int i=tid;i<512;i+=1024) lh[i]=0u;
  __syncthreads();
  int D0 = (int)ws[OSEL], D1 = (int)ws[OSEL+1];
  for(int ch=0;ch<2;++ch){
    u32 n = ws[OCNT+ch]; if(n > CAPP) n = CAPP;
    int D = ch ? D1 : D0;
    for(u32 i = blockIdx.x*1024 + tid; i < n; i += gridDim.x*1024){
      u32 idx = ws[OPK + ch*CAPP + i];
      u32 e = enc16(hm[idx] >> (16*ch));
      if((int)(e>>8) == D) atomicAdd(&lh[ch*256 + (e&255)], 1u);
    }
  }
  __syncthreads();
  for(int i=tid;i<512;i+=1024) if(lh[i]) atomicAdd(&ws[OH2+i], lh[i]);
}

__global__ void sel_lsd_kernel(u32* __restrict__ ws){
  __shared__ u32 h[512];
  int t = threadIdx.x;
  h[t] = ws[OH2+t];
  __syncthreads();
  if(t < 2){
    int D = (int)ws[OSEL+t];
    int need2 = TOPK - (int)ws[OSEL+2+t];   // in [1,100]
    const u32* hh = h + t*256;
    u32 above = 0; int L = 0;
    for(int b=255;b>=1;--b){
      if((int)(above + hh[b]) >= need2){ L = b; break; }
      above += hh[b];
    }
    ws[OSEL+4+t] = (u32)((D<<8) | L);       // full 16-bit enc threshold
  }
}

// collect: enc>thr -> listB (u64 keys, <=99); enc==thr -> contiguous tie list
__global__ __launch_bounds__(1024) void collect_kernel(const u32* __restrict__ hm, u32* __restrict__ ws){
  __shared__ u32 tbuf[2][2048];
  __shared__ u32 tcnt[2], tbase[2];
  int tid = threadIdx.x, lane = tid & 63;
  if(tid<2) tcnt[tid]=0u;
  __syncthreads();
  u32 thr0 = ws[OSEL+4], thr1 = ws[OSEL+5];
  u64* listB = (u64*)(ws + OLB);
  u32 total = gridDim.x*1024;
  for(int ch=0;ch<2;++ch){
    u32 n = ws[OCNT+ch]; if(n > CAPP) n = CAPP;
    u32 thr = ch ? thr1 : thr0;
    for(u32 base = blockIdx.x*1024; base < n; base += total){
      u32 i = base + tid;
      bool act = (i < n);
      u32 idx = 0, e = 0;
      if(act){ idx = ws[OPK + ch*CAPP + i]; e = enc16(hm[idx] >> (16*ch)); }
      if(act && e > thr){
        u32 pos = atomicAdd(&ws[OCNT+2+ch], 1u);
        if(pos < CAPB) listB[ch*CAPB + pos] = ((u64)e<<32) | (u32)(~idx);
      }
      bool isT = act && (e == thr);
      u64 mk = __ballot(isT);
      if(mk){
        u32 cntw = __popcll(mk), b;
        if(lane==0) b = atomicAdd(&tcnt[ch], cntw);
        b = __shfl(b, 0);
        if(isT){
          u32 pos = b + __popcll(mk & ((1ull<<lane)-1ull));
          if(pos < 2048) tbuf[ch][pos] = idx;
        }
      }
    }
  }
  __syncthreads();
  if(tid < 2){
    u32 c = tcnt[tid]; if(c > 2048) c = 2048;
    tcnt[tid] = c;
    tbase[tid] = atomicAdd(&ws[OCNT+4+tid], c);
  }
  __syncthreads();
  for(int ch=0;ch<2;++ch)
    for(u32 i=tid;i<tcnt[ch];i+=1024){
      u32 g = tbase[ch] + i;
      if(g < CAPT) ws[OLT + ch*CAPT + g] = tbuf[ch][i];
    }
}

// Low-barrier finalize: rank-sorts, wave-scan boundary select, bitmask NMS.
__global__ __launch_bounds__(1024) void finalize_kernel(
    u32* __restrict__ ws, const u32* __restrict__ szm, const u16* __restrict__ offm,
    const u16* __restrict__ orig, u16* __restrict__ out){
  __shared__ u32 cnts[8];            // cntP0,cntP1,cntB0,cntB1,cntT0,cntT1,thr0,thr1
  __shared__ u64 keysL[CAPB];
  __shared__ u32 h2[2048];
  __shared__ u32 wbits[64];
  __shared__ u32 sel[CAPB];
  __shared__ int Bv, cntBelowS, selc;
  __shared__ float oval[TOPK]; __shared__ int oidx[TOPK];
  __shared__ float nval[TOPK]; __shared__ int nidx[TOPK];
  __shared__ float cbox[TOPK][4]; __shared__ float cscore[TOPK]; __shared__ float area[TOPK];
  __shared__ int sup[TOPK]; __shared__ int slotv[TOPK];
  __shared__ u64 nbits[2*TOPK];
  __shared__ u64 suppS[2];
  __shared__ int cS, srS, scS, meanr, meanc;
  int tid = threadIdx.x, lane = tid & 63;
  const u64* listB = (const u64*)(ws + OLB);

  if(tid < 6) cnts[tid] = ws[OCNT+tid];
  if(tid < 2) cnts[6+tid] = ws[OSEL+4+tid];
  if(tid < TOPK){ oval[tid]=0.0f; oidx[tid]=0; nval[tid]=0.0f; nidx[tid]=0; }
  __syncthreads();

  for(int ch=0; ch<2; ++ch){
    int nB = (int)cnts[2+ch]; if(nB > CAPB) nB = CAPB; if(nB > TOPK) nB = TOPK;
    u32 thr = cnts[6+ch];
    float tval = up16(dec16(thr));
    float* dval = ch ? nval : oval;
    int*   didx = ch ? nidx : oidx;

    // ---- rank-sort listB (keys unique) straight into output slots ----
    u64 kreg = 0;
    if(tid < nB){ kreg = listB[ch*CAPB + tid]; keysL[tid] = kreg; }
    // zero tie scratch in same phase
    for(int i=tid;i<2048;i+=1024) h2[i]=0u;
    if(tid < 64) wbits[tid]=0u;
    if(tid == 0){ selc = 0; Bv = 0; cntBelowS = 0; }
    __syncthreads();
    if(tid < nB){
      int r = 0;
      for(int j=0;j<nB;++j) r += (keysL[j] > kreg);
      dval[r] = up16(dec16((u32)(kreg>>32)));
      didx[r] = (int)(~(u32)(kreg & 0xFFFFFFFFu));
    }
    int need = TOPK - nB;

    if(need > 0){
      int nT = (int)cnts[4+ch]; if(nT > CAPT) nT = CAPT;
      const u32* seg = ws + OLT + ch*CAPT;
      for(int i=tid;i<nT;i+=1024) atomicAdd(&h2[seg[i]>>11], 1u);
      __syncthreads();
      // ---- wave-0 scan: find smallest bin B with cum >= need ----
      if(tid < 64){
        int base = tid*32;
        u32 s = 0;
        #pragma unroll
        for(int k2=0;k2<32;++k2) s += h2[base+k2];
        u32 c = s;
        #pragma unroll
        for(int off=1;off<64;off<<=1){
          u32 v = __shfl_up(c, off, 64);
          if(lane >= off) c += v;
        }
        u64 m = __ballot(c >= (u32)need);
        int L = (int)(__ffsll((unsigned long long)m) - 1);
        if(tid == L){
          u32 cum2 = c - s;
          int B = base;
          for(int k2=0;k2<32;++k2){
            u32 hb = h2[base+k2];
            if(cum2 + hb >= (u32)need){ B = base+k2; break; }
            cum2 += hb;
          }
          Bv = B; cntBelowS = (int)cum2;
        }
      }
      __syncthreads();
      int B = Bv;
      for(int i=tid;i<nT;i+=1024){
        u32 idx = seg[i];
        int b = (int)(idx>>11);
        if(b < B){
          int pos = atomicAdd(&selc, 1);
          if(pos < CAPB) sel[pos] = idx;
        } else if(b == B){
          atomicOr(&wbits[(idx&2047)>>5], 1u<<(idx&31));
        }
      }
      __syncthreads();
      int sc = selc; if(sc > CAPB) sc = CAPB;
      // rank-sort below-B indices ascending into slots nB+r
      if(tid < sc){
        u32 v = sel[tid];
        int r = 0;
        for(int j=0;j<sc;++j) r += (sel[j] < v);
        if(nB + r < TOPK){ dval[nB+r] = tval; didx[nB+r] = (int)v; }
      }
      // bin-B bitmap extraction in ascending order (all > below-B indices)
      if(tid == 0){
        int rem = need - sc;
        int pos = nB + sc;
        for(int wi=0; wi<64 && rem>0; ++wi){
          u32 bits = wbits[wi];
          while(bits && rem>0){
            int l = __ffs(bits) - 1;
            bits &= bits - 1;
            if(pos < TOPK){ dval[pos] = tval; didx[pos] = (int)(((u32)B<<11) | ((u32)wi<<5) | (u32)l); }
            ++pos; --rem;
          }
        }
      }
    }
    __syncthreads();
  }

  float ry = up16(orig[0]) / 1536.0f;
  float rx = up16(orig[1]) / 1536.0f;

  // ---- nose stats (parallel) ----
  if(tid == 0){ cS = 0; srS = 0; scS = 0; }
  __syncthreads();
  if(tid < TOPK && nval[tid] > 0.5f){
    atomicAdd(&cS, 1);
    atomicAdd(&srS, nidx[tid] / IW);
    atomicAdd(&scS, nidx[tid] % IW);
  }
  if(tid < TOPK) out[610 + tid] = f2bf(nval[tid] > 0.5f ? nval[tid] : -1.0f);
  __syncthreads();
  if(tid == 0){
    int c = cS < 1 ? 1 : cS;
    meanr = srS / c; meanc = scS / c;
  }

  // ---- box decode ----
  if(tid < TOPK){
    int idx = oidx[tid];
    int r = idx / IW, c = idx - r*IW;
    float score = oval[tid];
    u32 sz = szm[idx];
    float sy = up16(sz), sx = up16(sz>>16);
    float cy = (float)r, cx = (float)c;
    float tly = fmaxf(cy - sy*0.5f, 0.0f);
    float tlx = fmaxf(cx - sx*0.5f, 0.0f);
    float bry = fminf(cy + sy*0.5f, 1535.0f);
    float brx = fminf(cx + sx*0.5f, 1535.0f);
    bool mk = score > 0.3f;
    float b0 = mk ? tly*ry : -1.0f;
    float b1 = mk ? tlx*rx : -1.0f;
    float b2 = mk ? bry*ry : -1.0f;
    float b3 = mk ? brx*rx : -1.0f;
    cbox[tid][0]=b0; cbox[tid][1]=b1; cbox[tid][2]=b2; cbox[tid][3]=b3;
    cscore[tid] = mk ? score : -1.0f;
    area[tid] = fmaxf(b2-b0,0.0f) * fmaxf(b3-b1,0.0f);
  }
  if(tid < 2*TOPK) nbits[tid] = 0ull;
  __syncthreads();

  // ---- bitmask NMS: parallel IoU pairs, then serial 128-bit recurrence ----
  for(int t=tid; t<TOPK*TOPK; t+=1024){
    int i = t / TOPK, j = t - i*TOPK;
    if(j > i){
      float iy1 = fmaxf(cbox[i][0], cbox[j][0]);
      float ix1 = fmaxf(cbox[i][1], cbox[j][1]);
      float iy2 = fminf(cbox[i][2], cbox[j][2]);
      float ix2 = fminf(cbox[i][3], cbox[j][3]);
      float inter = fmaxf(iy2-iy1,0.0f) * fmaxf(ix2-ix1,0.0f);
      float uni = (area[i] + area[j]) - inter;
      if(inter / fmaxf(uni, 1e-8f) > 0.5f)
        atomicOr(&nbits[i*2 + (j>>6)], 1ull << (j&63));
    }
  }
  __syncthreads();
  if(tid == 0){
    u64 s0 = 0ull, s1 = 0ull;
    for(int i=0;i<TOPK;++i){
      bool su = (i<64) ? ((s0>>i)&1ull) : ((s1>>(i-64))&1ull);
      if(!su){ s0 |= nbits[i*2]; s1 |= nbits[i*2+1]; }
    }
    suppS[0] = s0; suppS[1] = s1;
  }
  __syncthreads();
  if(tid < TOPK) sup[tid] = (int)((suppS[tid>>6] >> (tid&63)) & 1ull);
  __syncthreads();

  // ---- stable partition via per-thread prefix counts ----
  if(tid < TOPK){
    int kbefore = 0, sbefore = 0, ktot = 0;
    for(int j=0;j<TOPK;++j){
      int sj = sup[j];
      ktot += (1 - sj);
      if(j < tid){ kbefore += (1 - sj); sbefore += sj; }
    }
    int slot = sup[tid] ? (ktot + sbefore) : kbefore;
    slotv[slot] = tid;
  }
  __syncthreads();

  // ---- b_bboxes output with -1/0 -> inf substitution ----
  if(tid < TOPK){
    int s = slotv[tid];
    bool ks = !sup[s];
    u16 row[6];
    if(ks){
      for(int d=0;d<4;++d){
        float v = cbox[s][d];
        row[d] = (v == -1.0f || v == 0.0f) ? (u16)BF_INF16 : f2bf(v);
      }
      row[4] = f2bf(cscore[s]);
    } else {
      for(int d=0;d<4;++d) row[d] = (u16)BF_INF16;
      row[4] = 0;
    }
    row[5] = 0;
    for(int d=0;d<6;++d) out[tid*6 + d] = row[d];
  }

  if(tid == 0){
    float lfy = (float)meanr, lfx = (float)meanc;
    out[600] = f2bf(lfy * ry);
    out[601] = f2bf(lfx * rx);
    const u16* op = offm + ((size_t)meanr*IW + meanc)*8;
    for(int p=0;p<4;++p){
      out[602 + p*2 + 0] = f2bf((lfy - up16(op[p*2+0])) * ry);
      out[602 + p*2 + 1] = f2bf((lfx - up16(op[p*2+1])) * rx);
    }
  }
}

extern "C" void kernel_launch(void* const* d_in, const int* in_sizes, int n_in,
                              void* d_out, int out_size, void* d_ws, size_t ws_size,
                              hipStream_t stream) {
  const u32* heat = (const u32*)d_in[0];   // bf16 pairs (ch1<<16|ch0) per pixel
  const u16* offm = (const u16*)d_in[1];
  const u32* szm  = (const u32*)d_in[2];
  const u16* orig = (const u16*)d_in[3];
  u16* out = (u16*)d_out;
  u32* ws = (u32*)d_ws;

  hipMemsetAsync(ws, 0, 1040*sizeof(u32), stream);   // hists + sel + counters
  scan_kernel<<<576, 1024, 0, stream>>>(heat, ws);
  sel_msd_kernel<<<1, 512, 0, stream>>>(ws);
  lsd_kernel<<<128, 1024, 0, stream>>>(heat, ws);
  sel_lsd_kernel<<<1, 512, 0, stream>>>(ws);
  collect_kernel<<<128, 1024, 0, stream>>>(heat, ws);
  finalize_kernel<<<1, 1024, 0, stream>>>(ws, szm, offm, orig, out);
}